// Round 18
// baseline (523.938 us; speedup 1.0000x reference)
//
#include <hip/hip_runtime.h>
#include <math.h>

#define IN_DIM 128
#define OUT_DIM 64

typedef __attribute__((ext_vector_type(8))) _Float16 f16x8;
typedef __attribute__((ext_vector_type(4))) float f32x4;
typedef __attribute__((ext_vector_type(4))) _Float16 half4;

#define WSCALE 32.0f
#define WINV   (1.0f / 32.0f)

__device__ __forceinline__ void async_copy16(void* lds, const void* g) {
    __builtin_amdgcn_global_load_lds(
        (const __attribute__((address_space(1))) unsigned int*)g,
        (__attribute__((address_space(3))) unsigned int*)lds, 16, 0, 0);
}

// ---------------------------------------------------------------------------
// CSR build (by dst). Self-loops handled implicitly downstream.
// ---------------------------------------------------------------------------
__global__ void count_deg_kernel(const int* __restrict__ dst, int* __restrict__ deg, int e) {
    int i = blockIdx.x * blockDim.x + threadIdx.x;
    if (i < e) atomicAdd(&deg[dst[i]], 1);
}

__global__ __launch_bounds__(1024)
void scan_offsets_kernel(const int* __restrict__ deg, int* __restrict__ offs, int n) {
    __shared__ int partial[1024];
    const int tid = threadIdx.x;
    const int chunk = (n + 1023) / 1024;
    const int lo = tid * chunk;
    const int hi = min(lo + chunk, n);
    int s = 0;
    for (int i = lo; i < hi; ++i) s += deg[i];
    partial[tid] = s;
    __syncthreads();
    for (int d = 1; d < 1024; d <<= 1) {
        int v = (tid >= d) ? partial[tid - d] : 0;
        __syncthreads();
        partial[tid] += v;
        __syncthreads();
    }
    int run = (tid == 0) ? 0 : partial[tid - 1];
    for (int i = lo; i < hi; ++i) { offs[i] = run; run += deg[i]; }
    if (hi == n) offs[n] = run;
}

__global__ void scatter_edges_kernel(const int* __restrict__ src, const int* __restrict__ dst,
                                     const int* __restrict__ offs, int* __restrict__ cursor,
                                     int* __restrict__ esrc, int e) {
    int i = blockIdx.x * blockDim.x + threadIdx.x;
    if (i < e) {
        int d = dst[i];
        int pos = offs[d] + atomicAdd(&cursor[d], 1);
        esrc[pos] = src[i];
    }
}

// ---------------------------------------------------------------------------
// x fp32 -> fp16 (layer-0 GEMM A operand).
// ---------------------------------------------------------------------------
__global__ void x_to_f16_kernel(const float* __restrict__ x, _Float16* __restrict__ out, size_t n4) {
    size_t i = (size_t)blockIdx.x * blockDim.x + threadIdx.x;
    if (i >= n4) return;
    float4 v = *(const float4*)&x[i * 4];
    half4 h;
    h[0] = (_Float16)v.x; h[1] = (_Float16)v.y; h[2] = (_Float16)v.z; h[3] = (_Float16)v.w;
    *(half4*)&out[i * 4] = h;
}

// ---------------------------------------------------------------------------
// W [K][Nc] fp32 -> Wt [Nc][K] fp16 (transposed), scaled x32 (undone by WINV).
// ---------------------------------------------------------------------------
__global__ __launch_bounds__(256)
void transpose_f16(const float* __restrict__ W, _Float16* __restrict__ out,
                   int K, int Nc) {
    __shared__ float t[32][33];
    const int k0 = blockIdx.x * 32, n0 = blockIdx.y * 32;
    const int tx = threadIdx.x, ty = threadIdx.y;   // (32,8)
    #pragma unroll
    for (int j = 0; j < 32; j += 8)
        t[ty + j][tx] = W[(size_t)(k0 + ty + j) * Nc + n0 + tx];
    __syncthreads();
    #pragma unroll
    for (int j = 0; j < 32; j += 8)
        out[(size_t)(n0 + ty + j) * K + k0 + tx] = (_Float16)(t[tx][ty + j] * WSCALE);
}

// ---------------------------------------------------------------------------
// fp16 MFMA GEMM: BK=128 single-buffered (R10 structure) + bijective XCD
// swizzle (T1, R16-proven). Now that the swizzle fixes cross-XCD A-refetch,
// the loop is barrier-bound -> fewer/fatter K-steps win (R9/R10 lesson):
// 8 K-steps at K=1024, 64 MFMA per barrier pair.
// 128x128 tile, 4 waves, 256 thr, 16x16x32_f16, 1 MFMA per acc.
// LDS: A 32 KB + B 32 KB = 64 KB -> 2 blocks/CU.
// Row swizzle (256-B rows): byte ^= (row&15)<<4, pre-applied to global source.
// Output: C16 head-major (layers 0-2) or fp32 row-major guarded (layer 3).
// Fused alpha epilogue on both paths (guarded cb < Nc).
// ---------------------------------------------------------------------------
__global__ __launch_bounds__(256, 2)
void gemm_f16_mfma(const _Float16* __restrict__ A, const _Float16* __restrict__ Wt,
                   float* __restrict__ C, _Float16* __restrict__ C16,
                   int Nc, int K, size_t hstride16, int ncols,
                   const float* __restrict__ Asrc, const float* __restrict__ Adst,
                   float* __restrict__ as_out, float* __restrict__ ad_out, int Nrows) {
    __shared__ char smem[65536];          // A 32 KB | B 32 KB
    char* const sB = smem + 32768;

    const int tid = threadIdx.x;
    const int w = tid >> 6;
    const int lane = tid & 63;
    const int wr = w >> 1, wc = w & 1;

    // ---- bijective XCD swizzle (m204) ----
    const int nwg = gridDim.x;
    const int bid = blockIdx.x;
    const int xcd = bid & 7;
    const int lin = bid >> 3;
    const int q = nwg >> 3, r = nwg & 7;
    const int wk = (xcd < r ? xcd * (q + 1) : r * (q + 1) + (xcd - r) * q) + lin;
    const int bcol = (wk % ncols) * 128;
    const int brow = (wk / ncols) * 128;

    const size_t rb = (size_t)K * 2;

    // staging: 8 instrs/lane/operand/tile (32 KB tile, 256-B rows)
    int rr[8], bs[8], ldso[8];
    #pragma unroll
    for (int i = 0; i < 8; ++i) {
        int d = w * 8192 + i * 1024 + lane * 16;
        ldso[i] = d;
        rr[i] = d >> 8;
        bs[i] = (d & 255) ^ ((rr[i] & 15) << 4);
    }

    const char* gA = (const char*)A  + (size_t)brow * rb;
    const char* gB = (const char*)Wt + (size_t)bcol * rb;

    f32x4 acc[4][4];
    #pragma unroll
    for (int i = 0; i < 4; ++i)
        #pragma unroll
        for (int j = 0; j < 4; ++j) acc[i][j] = (f32x4)0.f;

    for (int k0 = 0; k0 < K; k0 += 128) {
        __syncthreads();
        const size_t kb = (size_t)k0 * 2;
        #pragma unroll
        for (int i = 0; i < 8; ++i) {
            const size_t goff = (size_t)rr[i] * rb + kb + bs[i];
            async_copy16(smem + ldso[i], gA + goff);
            async_copy16(sB + ldso[i],   gB + goff);
        }
        __syncthreads();

        #pragma unroll
        for (int kk = 0; kk < 4; ++kk) {
            f16x8 a[4], b[4];
            const int kbyte = kk * 64 + ((lane >> 4) * 16);
            #pragma unroll
            for (int f = 0; f < 4; ++f) {
                const int ra = wr * 64 + f * 16 + (lane & 15);
                a[f] = *(const f16x8*)(smem + ra * 256 + (kbyte ^ ((ra & 15) << 4)));
                const int rbn = wc * 64 + f * 16 + (lane & 15);
                b[f] = *(const f16x8*)(sB + rbn * 256 + (kbyte ^ ((rbn & 15) << 4)));
            }
            #pragma unroll
            for (int m = 0; m < 4; ++m)
                #pragma unroll
                for (int n = 0; n < 4; ++n)
                    acc[m][n] = __builtin_amdgcn_mfma_f32_16x16x32_f16(a[m], b[n], acc[m][n], 0, 0, 0);
        }
    }

    // undo the W x32 scale
    #pragma unroll
    for (int m = 0; m < 4; ++m)
        #pragma unroll
        for (int n = 0; n < 4; ++n) acc[m][n] *= WINV;

    const int rowb = brow + wr * 64 + ((lane >> 4) * 4);
    const int colb = bcol + wc * 64 + (lane & 15);
    if (C16) {
        #pragma unroll
        for (int m = 0; m < 4; ++m)
            #pragma unroll
            for (int n = 0; n < 4; ++n) {
                const int col = colb + n * 16;
                const size_t base = (size_t)(col >> 8) * hstride16 + (size_t)(col & 255);
                #pragma unroll
                for (int j = 0; j < 4; ++j)
                    C16[base + (size_t)(rowb + m * 16 + j) * 256] = (_Float16)acc[m][n][j];
            }
    } else {
        #pragma unroll
        for (int m = 0; m < 4; ++m)
            #pragma unroll
            for (int n = 0; n < 4; ++n) {
                const int col = colb + n * 16;
                if (col < Nc) {
                    #pragma unroll
                    for (int j = 0; j < 4; ++j)
                        C[(size_t)(rowb + m * 16 + j) * Nc + col] = acc[m][n][j];
                }
            }
    }

    // fused alpha: dot of exact fp32 acc tile with a_src/a_dst (both paths)
    const int cb = bcol + wc * 64;
    if (as_out && cb < Nc) {
        const int lcol = lane & 15;
        const int head = cb >> 8;
        float as4[4], ad4[4];
        #pragma unroll
        for (int n = 0; n < 4; ++n) {
            as4[n] = Asrc[cb + n * 16 + lcol];
            ad4[n] = Adst[cb + n * 16 + lcol];
        }
        #pragma unroll
        for (int m = 0; m < 4; ++m)
            #pragma unroll
            for (int j = 0; j < 4; ++j) {
                float ps = acc[m][0][j] * as4[0] + acc[m][1][j] * as4[1]
                         + acc[m][2][j] * as4[2] + acc[m][3][j] * as4[3];
                float pd = acc[m][0][j] * ad4[0] + acc[m][1][j] * ad4[1]
                         + acc[m][2][j] * ad4[2] + acc[m][3][j] * ad4[3];
                #pragma unroll
                for (int o = 1; o < 16; o <<= 1) {
                    ps += __shfl_xor(ps, o);
                    pd += __shfl_xor(pd, o);
                }
                if (lcol == 0) {
                    const int row = rowb + m * 16 + j;
                    if (row < Nrows) {
                        atomicAdd(&as_out[(size_t)head * Nrows + row], ps);
                        atomicAdd(&ad_out[(size_t)head * Nrows + row], pd);
                    }
                }
            }
    }
}

// ---------------------------------------------------------------------------
// Fused SpMM, single-pass, NO max subtraction (logits range-bounded; R13/R14-
// verified). Accumulate unnormalized acc += exp(e)*h and wave-uniform sum;
// single inv post-scale. (R16 version: R17's lane-split was null -- the
// kernel is memory-path bound at ~9.2 TB/s logical gather.)
// ---------------------------------------------------------------------------
__global__ __launch_bounds__(64)
void spmm16_kernel(const _Float16* __restrict__ h,   // [4][hm][256]
                   const float* __restrict__ as_,    // [4][N]
                   const float* __restrict__ ad_,
                   const int* __restrict__ offs, const int* __restrict__ esrc,
                   const float* __restrict__ bias,   // [4*256]
                   int N, int hm,
                   _Float16* __restrict__ out16) {   // [Mp][1024] row-major
    const int n = blockIdx.x;
    const int w = blockIdx.y;
    const int lane = threadIdx.x;

    const _Float16* hw = h + (size_t)w * hm * 256;
    const float* asw = as_ + (size_t)w * N;
    const float ad  = ad_[(size_t)w * N + n];

    float e0 = asw[n] + ad;
    e0 = (e0 > 0.f) ? e0 : 0.2f * e0;
    const int lo = offs[n], hi = offs[n + 1];

    float sum;
    float acc0, acc1, acc2, acc3;
    {
        const float p0 = __expf(e0);
        sum = p0;
        half4 t = *(const half4*)(hw + (size_t)n * 256 + lane * 4);
        acc0 = p0 * (float)t[0]; acc1 = p0 * (float)t[1];
        acc2 = p0 * (float)t[2]; acc3 = p0 * (float)t[3];
    }

    int j = lo;
    for (; j + 4 <= hi; j += 4) {
        const int s0 = esrc[j], s1 = esrc[j + 1], s2 = esrc[j + 2], s3 = esrc[j + 3];
        const half4 r0 = *(const half4*)(hw + (size_t)s0 * 256 + lane * 4);
        const half4 r1 = *(const half4*)(hw + (size_t)s1 * 256 + lane * 4);
        const half4 r2 = *(const half4*)(hw + (size_t)s2 * 256 + lane * 4);
        const half4 r3 = *(const half4*)(hw + (size_t)s3 * 256 + lane * 4);
        float e, p0, p1, p2, p3;
        e = asw[s0] + ad; e = (e > 0.f) ? e : 0.2f * e; p0 = __expf(e);
        e = asw[s1] + ad; e = (e > 0.f) ? e : 0.2f * e; p1 = __expf(e);
        e = asw[s2] + ad; e = (e > 0.f) ? e : 0.2f * e; p2 = __expf(e);
        e = asw[s3] + ad; e = (e > 0.f) ? e : 0.2f * e; p3 = __expf(e);
        sum += (p0 + p1) + (p2 + p3);
        acc0 += p0 * (float)r0[0] + p1 * (float)r1[0] + p2 * (float)r2[0] + p3 * (float)r3[0];
        acc1 += p0 * (float)r0[1] + p1 * (float)r1[1] + p2 * (float)r2[1] + p3 * (float)r3[1];
        acc2 += p0 * (float)r0[2] + p1 * (float)r1[2] + p2 * (float)r2[2] + p3 * (float)r3[2];
        acc3 += p0 * (float)r0[3] + p1 * (float)r1[3] + p2 * (float)r2[3] + p3 * (float)r3[3];
    }
    for (; j < hi; ++j) {
        const int s = esrc[j];
        float e = asw[s] + ad;
        e = (e > 0.f) ? e : 0.2f * e;
        const float p = __expf(e);
        sum += p;
        half4 t = *(const half4*)(hw + (size_t)s * 256 + lane * 4);
        acc0 += p * (float)t[0]; acc1 += p * (float)t[1];
        acc2 += p * (float)t[2]; acc3 += p * (float)t[3];
    }

    const float inv = 1.0f / (sum + 1e-16f);
    float v0 = acc0 * inv + bias[w * 256 + lane * 4 + 0];
    float v1 = acc1 * inv + bias[w * 256 + lane * 4 + 1];
    float v2 = acc2 * inv + bias[w * 256 + lane * 4 + 2];
    float v3 = acc3 * inv + bias[w * 256 + lane * 4 + 3];
    v0 = (v0 > 0.f) ? v0 : (__expf(v0) - 1.0f);
    v1 = (v1 > 0.f) ? v1 : (__expf(v1) - 1.0f);
    v2 = (v2 > 0.f) ? v2 : (__expf(v2) - 1.0f);
    v3 = (v3 > 0.f) ? v3 : (__expf(v3) - 1.0f);

    half4 hv;
    hv[0] = (_Float16)v0; hv[1] = (_Float16)v1;
    hv[2] = (_Float16)v2; hv[3] = (_Float16)v3;
    *(half4*)&out16[(size_t)n * 1024 + (size_t)w * 256 + lane * 4] = hv;
}

// ---------------------------------------------------------------------------
// Final layer: fp32 h [N][64], 1 head, no ELU, fp32 out. No-max form (R13+).
// ---------------------------------------------------------------------------
__global__ __launch_bounds__(64)
void spmm32_kernel(const float* __restrict__ h,
                   const float* __restrict__ as_, const float* __restrict__ ad_,
                   const int* __restrict__ offs, const int* __restrict__ esrc,
                   const float* __restrict__ bias,
                   int N, float* __restrict__ out) {
    const int n = blockIdx.x;
    const int lane = threadIdx.x;

    const float ad  = ad_[n];
    float e0 = as_[n] + ad;
    e0 = (e0 > 0.f) ? e0 : 0.2f * e0;
    const int lo = offs[n], hi = offs[n + 1];

    float sum;
    float acc;
    {
        const float p0 = __expf(e0);
        sum = p0;
        acc = p0 * h[(size_t)n * 64 + lane];
    }

    int j = lo;
    for (; j + 4 <= hi; j += 4) {
        const int s0 = esrc[j], s1 = esrc[j + 1], s2 = esrc[j + 2], s3 = esrc[j + 3];
        const float r0 = h[(size_t)s0 * 64 + lane];
        const float r1 = h[(size_t)s1 * 64 + lane];
        const float r2 = h[(size_t)s2 * 64 + lane];
        const float r3 = h[(size_t)s3 * 64 + lane];
        float e, p0, p1, p2, p3;
        e = as_[s0] + ad; e = (e > 0.f) ? e : 0.2f * e; p0 = __expf(e);
        e = as_[s1] + ad; e = (e > 0.f) ? e : 0.2f * e; p1 = __expf(e);
        e = as_[s2] + ad; e = (e > 0.f) ? e : 0.2f * e; p2 = __expf(e);
        e = as_[s3] + ad; e = (e > 0.f) ? e : 0.2f * e; p3 = __expf(e);
        sum += (p0 + p1) + (p2 + p3);
        acc += p0 * r0 + p1 * r1 + p2 * r2 + p3 * r3;
    }
    for (; j < hi; ++j) {
        const int s = esrc[j];
        float e = as_[s] + ad;
        e = (e > 0.f) ? e : 0.2f * e;
        const float p = __expf(e);
        sum += p;
        acc += p * h[(size_t)s * 64 + lane];
    }

    out[(size_t)n * 64 + lane] = acc / (sum + 1e-16f) + bias[lane];
}

// ---------------------------------------------------------------------------
extern "C" void kernel_launch(void* const* d_in, const int* in_sizes, int n_in,
                              void* d_out, int out_size, void* d_ws, size_t ws_size,
                              hipStream_t stream) {
    const float* x    = (const float*)d_in[0];
    const int*   edge = (const int*)d_in[1];
    const int N = in_sizes[0] / IN_DIM;
    const int E = in_sizes[1] / 2;
    const int Mp = ((N + 127) / 128) * 128;

    const float* W[4]; const float* As[4]; const float* Ad[4]; const float* Bb[4];
    for (int i = 0; i < 4; ++i) {
        W[i]  = (const float*)d_in[2 + 4 * i];
        As[i] = (const float*)d_in[3 + 4 * i];
        Ad[i] = (const float*)d_in[4 + 4 * i];
        Bb[i] = (const float*)d_in[5 + 4 * i];
    }

    char* ws = (char*)d_ws;
    auto alloc = [&](size_t bytes) {
        char* p = ws;
        ws += (bytes + 255) & ~(size_t)255;
        return p;
    };
    _Float16*  h16   = (_Float16*)alloc((size_t)4 * Mp * 256 * 2);   // GEMM out, fp16 head-major
    _Float16*  X16   = (_Float16*)alloc((size_t)Mp * 1024 * 2);      // layer input (GEMM A), fp16
    float*     bufA  = (float*)alloc((size_t)Mp * OUT_DIM * 4);      // layer-3 GEMM out
    _Float16*  Wt    = (_Float16*)alloc((size_t)1024 * 1024 * 2);    // transposed fp16 W (x32)
    float*     as_buf = (float*)alloc((size_t)N * 4 * 4);
    float*     ad_buf = (float*)alloc((size_t)N * 4 * 4);
    int*       deg    = (int*)alloc((size_t)(N + 1) * 4);
    int*       offs   = (int*)alloc((size_t)(N + 1) * 4);
    int*       cursor = (int*)alloc((size_t)N * 4);
    int*       esrc   = (int*)alloc((size_t)E * 4);
    (void)ws_size;

    const int* e_src = edge;
    const int* e_dst = edge + E;

    // ---- CSR build ----
    hipMemsetAsync(deg, 0, (size_t)N * 4, stream);
    count_deg_kernel<<<(E + 255) / 256, 256, 0, stream>>>(e_dst, deg, E);
    scan_offsets_kernel<<<1, 1024, 0, stream>>>(deg, offs, N);
    hipMemsetAsync(cursor, 0, (size_t)N * 4, stream);
    scatter_edges_kernel<<<(E + 255) / 256, 256, 0, stream>>>(e_src, e_dst, offs, cursor, esrc, E);

    // ---- zero pad rows of the X16 views ----
    hipMemsetAsync((char*)X16 + (size_t)N * 256, 0, (size_t)(Mp - N) * 256, stream);
    hipMemsetAsync((char*)X16 + (size_t)N * 2048, 0, (size_t)(Mp - N) * 2048, stream);

    // ---- layer 0 input -> fp16 ----
    {
        size_t n4 = (size_t)N * IN_DIM / 4;
        x_to_f16_kernel<<<(unsigned)((n4 + 255) / 256), 256, 0, stream>>>(x, X16, n4);
    }

    const dim3 tblk(32, 8);
    const int gx = Mp / 128;
    const size_t hstride16 = (size_t)Mp * 256;
    const size_t abytes = (size_t)N * 4 * 4;

    // ---- Layer 0 (K=128: single K-step) ----
    transpose_f16<<<dim3(IN_DIM / 32, 1024 / 32), tblk, 0, stream>>>(W[0], Wt, IN_DIM, 1024);
    hipMemsetAsync(as_buf, 0, abytes, stream);
    hipMemsetAsync(ad_buf, 0, abytes, stream);
    gemm_f16_mfma<<<8 * gx, 256, 0, stream>>>(X16, Wt, nullptr, h16, 1024, IN_DIM, hstride16, 8,
                                              As[0], Ad[0], as_buf, ad_buf, N);
    spmm16_kernel<<<dim3(N, 4), 64, 0, stream>>>(
        h16, as_buf, ad_buf, offs, esrc, Bb[0], N, Mp, X16);

    // ---- Layers 1,2 ----
    for (int l = 1; l <= 2; ++l) {
        transpose_f16<<<dim3(1024 / 32, 1024 / 32), tblk, 0, stream>>>(W[l], Wt, 1024, 1024);
        hipMemsetAsync(as_buf, 0, abytes, stream);
        hipMemsetAsync(ad_buf, 0, abytes, stream);
        gemm_f16_mfma<<<8 * gx, 256, 0, stream>>>(X16, Wt, nullptr, h16, 1024, 1024, hstride16, 8,
                                                  As[l], Ad[l], as_buf, ad_buf, N);
        spmm16_kernel<<<dim3(N, 4), 64, 0, stream>>>(
            h16, as_buf, ad_buf, offs, esrc, Bb[l], N, Mp, X16);
    }

    // ---- Layer 3: K=1024 -> h(64), 1 head, fp32 out; alpha fused in GEMM ----
    hipMemsetAsync(Wt, 0, (size_t)128 * 1024 * 2, stream);   // zero cols 64..127 of the padded tile
    transpose_f16<<<dim3(1024 / 32, OUT_DIM / 32), tblk, 0, stream>>>(W[3], Wt, 1024, OUT_DIM);
    hipMemsetAsync(as_buf, 0, abytes, stream);
    hipMemsetAsync(ad_buf, 0, abytes, stream);
    gemm_f16_mfma<<<gx, 256, 0, stream>>>(X16, Wt, bufA, nullptr, OUT_DIM, 1024, 0, 1,
                                          As[3], Ad[3], as_buf, ad_buf, N);
    spmm32_kernel<<<N, 64, 0, stream>>>(
        bufA, as_buf, ad_buf, offs, esrc, Bb[3], N, (float*)d_out);
}

// Round 19
// 509.007 us; speedup vs baseline: 1.0293x; 1.0293x over previous
//
#include <hip/hip_runtime.h>
#include <math.h>

#define IN_DIM 128
#define OUT_DIM 64

typedef __attribute__((ext_vector_type(8))) _Float16 f16x8;
typedef __attribute__((ext_vector_type(4))) float f32x4;
typedef __attribute__((ext_vector_type(4))) _Float16 half4;

#define WSCALE 32.0f
#define WINV   (1.0f / 32.0f)

__device__ __forceinline__ void async_copy16(void* lds, const void* g) {
    __builtin_amdgcn_global_load_lds(
        (const __attribute__((address_space(1))) unsigned int*)g,
        (__attribute__((address_space(3))) unsigned int*)lds, 16, 0, 0);
}

// ---------------------------------------------------------------------------
// CSR build (by dst). Self-loops handled implicitly downstream.
// ---------------------------------------------------------------------------
__global__ void count_deg_kernel(const int* __restrict__ dst, int* __restrict__ deg, int e) {
    int i = blockIdx.x * blockDim.x + threadIdx.x;
    if (i < e) atomicAdd(&deg[dst[i]], 1);
}

__global__ __launch_bounds__(1024)
void scan_offsets_kernel(const int* __restrict__ deg, int* __restrict__ offs, int n) {
    __shared__ int partial[1024];
    const int tid = threadIdx.x;
    const int chunk = (n + 1023) / 1024;
    const int lo = tid * chunk;
    const int hi = min(lo + chunk, n);
    int s = 0;
    for (int i = lo; i < hi; ++i) s += deg[i];
    partial[tid] = s;
    __syncthreads();
    for (int d = 1; d < 1024; d <<= 1) {
        int v = (tid >= d) ? partial[tid - d] : 0;
        __syncthreads();
        partial[tid] += v;
        __syncthreads();
    }
    int run = (tid == 0) ? 0 : partial[tid - 1];
    for (int i = lo; i < hi; ++i) { offs[i] = run; run += deg[i]; }
    if (hi == n) offs[n] = run;
}

__global__ void scatter_edges_kernel(const int* __restrict__ src, const int* __restrict__ dst,
                                     const int* __restrict__ offs, int* __restrict__ cursor,
                                     int* __restrict__ esrc, int e) {
    int i = blockIdx.x * blockDim.x + threadIdx.x;
    if (i < e) {
        int d = dst[i];
        int pos = offs[d] + atomicAdd(&cursor[d], 1);
        esrc[pos] = src[i];
    }
}

// ---------------------------------------------------------------------------
// x fp32 -> fp16 (layer-0 GEMM A operand).
// ---------------------------------------------------------------------------
__global__ void x_to_f16_kernel(const float* __restrict__ x, _Float16* __restrict__ out, size_t n4) {
    size_t i = (size_t)blockIdx.x * blockDim.x + threadIdx.x;
    if (i >= n4) return;
    float4 v = *(const float4*)&x[i * 4];
    half4 h;
    h[0] = (_Float16)v.x; h[1] = (_Float16)v.y; h[2] = (_Float16)v.z; h[3] = (_Float16)v.w;
    *(half4*)&out[i * 4] = h;
}

// ---------------------------------------------------------------------------
// W [K][Nc] fp32 -> Wt [Nc][K] fp16 (transposed), scaled x32 (undone by WINV).
// ---------------------------------------------------------------------------
__global__ __launch_bounds__(256)
void transpose_f16(const float* __restrict__ W, _Float16* __restrict__ out,
                   int K, int Nc) {
    __shared__ float t[32][33];
    const int k0 = blockIdx.x * 32, n0 = blockIdx.y * 32;
    const int tx = threadIdx.x, ty = threadIdx.y;   // (32,8)
    #pragma unroll
    for (int j = 0; j < 32; j += 8)
        t[ty + j][tx] = W[(size_t)(k0 + ty + j) * Nc + n0 + tx];
    __syncthreads();
    #pragma unroll
    for (int j = 0; j < 32; j += 8)
        out[(size_t)(n0 + ty + j) * K + k0 + tx] = (_Float16)(t[tx][ty + j] * WSCALE);
}

// ---------------------------------------------------------------------------
// fp16 MFMA GEMM, 2-phase double-buffered, bijective XCD swizzle (R16-proven
// optimum of the variant matrix {BK=32/64/128, +/-dbuf, 128^2/256x128,
// split-W, +/-swizzle}):
// 128x128 tile, BK=64, 4 waves, 256 thr, 16x16x32_f16, 1 MFMA per acc.
// LDS: 2 bufs x (A 16KB + B 16KB) = 64 KB -> 2 blocks/CU.
// Row swizzle (128-B rows): byte ^= (row&7)<<4, pre-applied to global source.
// Output: C16 head-major (layers 0-2) or fp32 row-major guarded (layer 3).
// Fused alpha epilogue on both paths (guarded cb < Nc).
// ---------------------------------------------------------------------------
__global__ __launch_bounds__(256, 2)
void gemm_f16_mfma(const _Float16* __restrict__ A, const _Float16* __restrict__ Wt,
                   float* __restrict__ C, _Float16* __restrict__ C16,
                   int Nc, int K, size_t hstride16, int ncols,
                   const float* __restrict__ Asrc, const float* __restrict__ Adst,
                   float* __restrict__ as_out, float* __restrict__ ad_out, int Nrows) {
    __shared__ char smem[65536];          // [2 bufs][A 16KB | B 16KB]

    const int tid = threadIdx.x;
    const int w = tid >> 6;
    const int lane = tid & 63;
    const int wr = w >> 1, wc = w & 1;

    // ---- bijective XCD swizzle (m204) ----
    const int nwg = gridDim.x;
    const int bid = blockIdx.x;
    const int xcd = bid & 7;
    const int lin = bid >> 3;
    const int q = nwg >> 3, r = nwg & 7;
    const int wk = (xcd < r ? xcd * (q + 1) : r * (q + 1) + (xcd - r) * q) + lin;
    const int bcol = (wk % ncols) * 128;
    const int brow = (wk / ncols) * 128;

    const size_t rb = (size_t)K * 2;

    int rr[4], bs[4], ldso[4];
    #pragma unroll
    for (int i = 0; i < 4; ++i) {
        int d = w * 4096 + i * 1024 + lane * 16;
        ldso[i] = d;
        rr[i] = d >> 7;
        bs[i] = (d & 127) ^ ((rr[i] & 7) << 4);
    }

    const char* gA = (const char*)A  + (size_t)brow * rb;
    const char* gB = (const char*)Wt + (size_t)bcol * rb;

    f32x4 acc[4][4];
    #pragma unroll
    for (int i = 0; i < 4; ++i)
        #pragma unroll
        for (int j = 0; j < 4; ++j) acc[i][j] = (f32x4)0.f;

    // ---- prologue: stage tile 0 into buf 0 ----
    #pragma unroll
    for (int i = 0; i < 4; ++i) {
        const size_t goff = (size_t)rr[i] * rb + bs[i];
        async_copy16(smem + ldso[i],         gA + goff);
        async_copy16(smem + 16384 + ldso[i], gB + goff);
    }
    __syncthreads();

    int cur = 0;
    for (int k0 = 0; k0 < K; k0 += 64) {
        if (k0 + 64 < K) {
            char* dA = smem + (cur ^ 1) * 32768;
            char* dB = dA + 16384;
            const size_t kb = (size_t)(k0 + 64) * 2;
            #pragma unroll
            for (int i = 0; i < 4; ++i) {
                const size_t goff = (size_t)rr[i] * rb + kb + bs[i];
                async_copy16(dA + ldso[i], gA + goff);
                async_copy16(dB + ldso[i], gB + goff);
            }
        }

        const char* sA = smem + cur * 32768;
        const char* sB = sA + 16384;
        #pragma unroll
        for (int kk = 0; kk < 2; ++kk) {
            f16x8 a[4], b[4];
            const int kbyte = kk * 64 + ((lane >> 4) * 16);
            #pragma unroll
            for (int f = 0; f < 4; ++f) {
                const int ra = wr * 64 + f * 16 + (lane & 15);
                a[f] = *(const f16x8*)(sA + ra * 128 + (kbyte ^ ((ra & 7) << 4)));
                const int rbn = wc * 64 + f * 16 + (lane & 15);
                b[f] = *(const f16x8*)(sB + rbn * 128 + (kbyte ^ ((rbn & 7) << 4)));
            }
            #pragma unroll
            for (int m = 0; m < 4; ++m)
                #pragma unroll
                for (int n = 0; n < 4; ++n)
                    acc[m][n] = __builtin_amdgcn_mfma_f32_16x16x32_f16(a[m], b[n], acc[m][n], 0, 0, 0);
        }

        __syncthreads();
        cur ^= 1;
    }

    // undo the W x32 scale
    #pragma unroll
    for (int m = 0; m < 4; ++m)
        #pragma unroll
        for (int n = 0; n < 4; ++n) acc[m][n] *= WINV;

    const int rowb = brow + wr * 64 + ((lane >> 4) * 4);
    const int colb = bcol + wc * 64 + (lane & 15);
    if (C16) {
        #pragma unroll
        for (int m = 0; m < 4; ++m)
            #pragma unroll
            for (int n = 0; n < 4; ++n) {
                const int col = colb + n * 16;
                const size_t base = (size_t)(col >> 8) * hstride16 + (size_t)(col & 255);
                #pragma unroll
                for (int j = 0; j < 4; ++j)
                    C16[base + (size_t)(rowb + m * 16 + j) * 256] = (_Float16)acc[m][n][j];
            }
    } else {
        #pragma unroll
        for (int m = 0; m < 4; ++m)
            #pragma unroll
            for (int n = 0; n < 4; ++n) {
                const int col = colb + n * 16;
                if (col < Nc) {
                    #pragma unroll
                    for (int j = 0; j < 4; ++j)
                        C[(size_t)(rowb + m * 16 + j) * Nc + col] = acc[m][n][j];
                }
            }
    }

    // fused alpha: dot of exact fp32 acc tile with a_src/a_dst (both paths)
    const int cb = bcol + wc * 64;
    if (as_out && cb < Nc) {
        const int lcol = lane & 15;
        const int head = cb >> 8;
        float as4[4], ad4[4];
        #pragma unroll
        for (int n = 0; n < 4; ++n) {
            as4[n] = Asrc[cb + n * 16 + lcol];
            ad4[n] = Adst[cb + n * 16 + lcol];
        }
        #pragma unroll
        for (int m = 0; m < 4; ++m)
            #pragma unroll
            for (int j = 0; j < 4; ++j) {
                float ps = acc[m][0][j] * as4[0] + acc[m][1][j] * as4[1]
                         + acc[m][2][j] * as4[2] + acc[m][3][j] * as4[3];
                float pd = acc[m][0][j] * ad4[0] + acc[m][1][j] * ad4[1]
                         + acc[m][2][j] * ad4[2] + acc[m][3][j] * ad4[3];
                #pragma unroll
                for (int o = 1; o < 16; o <<= 1) {
                    ps += __shfl_xor(ps, o);
                    pd += __shfl_xor(pd, o);
                }
                if (lcol == 0) {
                    const int row = rowb + m * 16 + j;
                    if (row < Nrows) {
                        atomicAdd(&as_out[(size_t)head * Nrows + row], ps);
                        atomicAdd(&ad_out[(size_t)head * Nrows + row], pd);
                    }
                }
            }
    }
}

// ---------------------------------------------------------------------------
// Fused SpMM, single-pass, NO max subtraction (logits range-bounded; R13/R14-
// verified). Accumulate unnormalized acc += exp(e)*h and wave-uniform sum;
// single inv post-scale. Memory-path bound at ~9.2 TB/s logical gather
// (R11/R15/R17 VALU-side changes all null).
// ---------------------------------------------------------------------------
__global__ __launch_bounds__(64)
void spmm16_kernel(const _Float16* __restrict__ h,   // [4][hm][256]
                   const float* __restrict__ as_,    // [4][N]
                   const float* __restrict__ ad_,
                   const int* __restrict__ offs, const int* __restrict__ esrc,
                   const float* __restrict__ bias,   // [4*256]
                   int N, int hm,
                   _Float16* __restrict__ out16) {   // [Mp][1024] row-major
    const int n = blockIdx.x;
    const int w = blockIdx.y;
    const int lane = threadIdx.x;

    const _Float16* hw = h + (size_t)w * hm * 256;
    const float* asw = as_ + (size_t)w * N;
    const float ad  = ad_[(size_t)w * N + n];

    float e0 = asw[n] + ad;
    e0 = (e0 > 0.f) ? e0 : 0.2f * e0;
    const int lo = offs[n], hi = offs[n + 1];

    float sum;
    float acc0, acc1, acc2, acc3;
    {
        const float p0 = __expf(e0);
        sum = p0;
        half4 t = *(const half4*)(hw + (size_t)n * 256 + lane * 4);
        acc0 = p0 * (float)t[0]; acc1 = p0 * (float)t[1];
        acc2 = p0 * (float)t[2]; acc3 = p0 * (float)t[3];
    }

    int j = lo;
    for (; j + 4 <= hi; j += 4) {
        const int s0 = esrc[j], s1 = esrc[j + 1], s2 = esrc[j + 2], s3 = esrc[j + 3];
        const half4 r0 = *(const half4*)(hw + (size_t)s0 * 256 + lane * 4);
        const half4 r1 = *(const half4*)(hw + (size_t)s1 * 256 + lane * 4);
        const half4 r2 = *(const half4*)(hw + (size_t)s2 * 256 + lane * 4);
        const half4 r3 = *(const half4*)(hw + (size_t)s3 * 256 + lane * 4);
        float e, p0, p1, p2, p3;
        e = asw[s0] + ad; e = (e > 0.f) ? e : 0.2f * e; p0 = __expf(e);
        e = asw[s1] + ad; e = (e > 0.f) ? e : 0.2f * e; p1 = __expf(e);
        e = asw[s2] + ad; e = (e > 0.f) ? e : 0.2f * e; p2 = __expf(e);
        e = asw[s3] + ad; e = (e > 0.f) ? e : 0.2f * e; p3 = __expf(e);
        sum += (p0 + p1) + (p2 + p3);
        acc0 += p0 * (float)r0[0] + p1 * (float)r1[0] + p2 * (float)r2[0] + p3 * (float)r3[0];
        acc1 += p0 * (float)r0[1] + p1 * (float)r1[1] + p2 * (float)r2[1] + p3 * (float)r3[1];
        acc2 += p0 * (float)r0[2] + p1 * (float)r1[2] + p2 * (float)r2[2] + p3 * (float)r3[2];
        acc3 += p0 * (float)r0[3] + p1 * (float)r1[3] + p2 * (float)r2[3] + p3 * (float)r3[3];
    }
    for (; j < hi; ++j) {
        const int s = esrc[j];
        float e = asw[s] + ad;
        e = (e > 0.f) ? e : 0.2f * e;
        const float p = __expf(e);
        sum += p;
        half4 t = *(const half4*)(hw + (size_t)s * 256 + lane * 4);
        acc0 += p * (float)t[0]; acc1 += p * (float)t[1];
        acc2 += p * (float)t[2]; acc3 += p * (float)t[3];
    }

    const float inv = 1.0f / (sum + 1e-16f);
    float v0 = acc0 * inv + bias[w * 256 + lane * 4 + 0];
    float v1 = acc1 * inv + bias[w * 256 + lane * 4 + 1];
    float v2 = acc2 * inv + bias[w * 256 + lane * 4 + 2];
    float v3 = acc3 * inv + bias[w * 256 + lane * 4 + 3];
    v0 = (v0 > 0.f) ? v0 : (__expf(v0) - 1.0f);
    v1 = (v1 > 0.f) ? v1 : (__expf(v1) - 1.0f);
    v2 = (v2 > 0.f) ? v2 : (__expf(v2) - 1.0f);
    v3 = (v3 > 0.f) ? v3 : (__expf(v3) - 1.0f);

    half4 hv;
    hv[0] = (_Float16)v0; hv[1] = (_Float16)v1;
    hv[2] = (_Float16)v2; hv[3] = (_Float16)v3;
    *(half4*)&out16[(size_t)n * 1024 + (size_t)w * 256 + lane * 4] = hv;
}

// ---------------------------------------------------------------------------
// Final layer: fp32 h [N][64], 1 head, no ELU, fp32 out. No-max form (R13+).
// ---------------------------------------------------------------------------
__global__ __launch_bounds__(64)
void spmm32_kernel(const float* __restrict__ h,
                   const float* __restrict__ as_, const float* __restrict__ ad_,
                   const int* __restrict__ offs, const int* __restrict__ esrc,
                   const float* __restrict__ bias,
                   int N, float* __restrict__ out) {
    const int n = blockIdx.x;
    const int lane = threadIdx.x;

    const float ad  = ad_[n];
    float e0 = as_[n] + ad;
    e0 = (e0 > 0.f) ? e0 : 0.2f * e0;
    const int lo = offs[n], hi = offs[n + 1];

    float sum;
    float acc;
    {
        const float p0 = __expf(e0);
        sum = p0;
        acc = p0 * h[(size_t)n * 64 + lane];
    }

    int j = lo;
    for (; j + 4 <= hi; j += 4) {
        const int s0 = esrc[j], s1 = esrc[j + 1], s2 = esrc[j + 2], s3 = esrc[j + 3];
        const float r0 = h[(size_t)s0 * 64 + lane];
        const float r1 = h[(size_t)s1 * 64 + lane];
        const float r2 = h[(size_t)s2 * 64 + lane];
        const float r3 = h[(size_t)s3 * 64 + lane];
        float e, p0, p1, p2, p3;
        e = as_[s0] + ad; e = (e > 0.f) ? e : 0.2f * e; p0 = __expf(e);
        e = as_[s1] + ad; e = (e > 0.f) ? e : 0.2f * e; p1 = __expf(e);
        e = as_[s2] + ad; e = (e > 0.f) ? e : 0.2f * e; p2 = __expf(e);
        e = as_[s3] + ad; e = (e > 0.f) ? e : 0.2f * e; p3 = __expf(e);
        sum += (p0 + p1) + (p2 + p3);
        acc += p0 * r0 + p1 * r1 + p2 * r2 + p3 * r3;
    }
    for (; j < hi; ++j) {
        const int s = esrc[j];
        float e = as_[s] + ad;
        e = (e > 0.f) ? e : 0.2f * e;
        const float p = __expf(e);
        sum += p;
        acc += p * h[(size_t)s * 64 + lane];
    }

    out[(size_t)n * 64 + lane] = acc / (sum + 1e-16f) + bias[lane];
}

// ---------------------------------------------------------------------------
extern "C" void kernel_launch(void* const* d_in, const int* in_sizes, int n_in,
                              void* d_out, int out_size, void* d_ws, size_t ws_size,
                              hipStream_t stream) {
    const float* x    = (const float*)d_in[0];
    const int*   edge = (const int*)d_in[1];
    const int N = in_sizes[0] / IN_DIM;
    const int E = in_sizes[1] / 2;
    const int Mp = ((N + 127) / 128) * 128;

    const float* W[4]; const float* As[4]; const float* Ad[4]; const float* Bb[4];
    for (int i = 0; i < 4; ++i) {
        W[i]  = (const float*)d_in[2 + 4 * i];
        As[i] = (const float*)d_in[3 + 4 * i];
        Ad[i] = (const float*)d_in[4 + 4 * i];
        Bb[i] = (const float*)d_in[5 + 4 * i];
    }

    char* ws = (char*)d_ws;
    auto alloc = [&](size_t bytes) {
        char* p = ws;
        ws += (bytes + 255) & ~(size_t)255;
        return p;
    };
    _Float16*  h16   = (_Float16*)alloc((size_t)4 * Mp * 256 * 2);   // GEMM out, fp16 head-major
    _Float16*  X16   = (_Float16*)alloc((size_t)Mp * 1024 * 2);      // layer input (GEMM A), fp16
    float*     bufA  = (float*)alloc((size_t)Mp * OUT_DIM * 4);      // layer-3 GEMM out
    _Float16*  Wt    = (_Float16*)alloc((size_t)1024 * 1024 * 2);    // transposed fp16 W (x32)
    float*     as_buf = (float*)alloc((size_t)N * 4 * 4);
    float*     ad_buf = (float*)alloc((size_t)N * 4 * 4);
    int*       deg    = (int*)alloc((size_t)(N + 1) * 4);
    int*       offs   = (int*)alloc((size_t)(N + 1) * 4);
    int*       cursor = (int*)alloc((size_t)N * 4);
    int*       esrc   = (int*)alloc((size_t)E * 4);
    (void)ws_size;

    const int* e_src = edge;
    const int* e_dst = edge + E;

    // ---- CSR build ----
    hipMemsetAsync(deg, 0, (size_t)N * 4, stream);
    count_deg_kernel<<<(E + 255) / 256, 256, 0, stream>>>(e_dst, deg, E);
    scan_offsets_kernel<<<1, 1024, 0, stream>>>(deg, offs, N);
    hipMemsetAsync(cursor, 0, (size_t)N * 4, stream);
    scatter_edges_kernel<<<(E + 255) / 256, 256, 0, stream>>>(e_src, e_dst, offs, cursor, esrc, E);

    // ---- zero pad rows of the X16 views ----
    hipMemsetAsync((char*)X16 + (size_t)N * 256, 0, (size_t)(Mp - N) * 256, stream);
    hipMemsetAsync((char*)X16 + (size_t)N * 2048, 0, (size_t)(Mp - N) * 2048, stream);

    // ---- layer 0 input -> fp16 ----
    {
        size_t n4 = (size_t)N * IN_DIM / 4;
        x_to_f16_kernel<<<(unsigned)((n4 + 255) / 256), 256, 0, stream>>>(x, X16, n4);
    }

    const dim3 tblk(32, 8);
    const int gx = Mp / 128;
    const size_t hstride16 = (size_t)Mp * 256;
    const size_t abytes = (size_t)N * 4 * 4;

    // ---- Layer 0 ----
    transpose_f16<<<dim3(IN_DIM / 32, 1024 / 32), tblk, 0, stream>>>(W[0], Wt, IN_DIM, 1024);
    hipMemsetAsync(as_buf, 0, abytes, stream);
    hipMemsetAsync(ad_buf, 0, abytes, stream);
    gemm_f16_mfma<<<8 * gx, 256, 0, stream>>>(X16, Wt, nullptr, h16, 1024, IN_DIM, hstride16, 8,
                                              As[0], Ad[0], as_buf, ad_buf, N);
    spmm16_kernel<<<dim3(N, 4), 64, 0, stream>>>(
        h16, as_buf, ad_buf, offs, esrc, Bb[0], N, Mp, X16);

    // ---- Layers 1,2 ----
    for (int l = 1; l <= 2; ++l) {
        transpose_f16<<<dim3(1024 / 32, 1024 / 32), tblk, 0, stream>>>(W[l], Wt, 1024, 1024);
        hipMemsetAsync(as_buf, 0, abytes, stream);
        hipMemsetAsync(ad_buf, 0, abytes, stream);
        gemm_f16_mfma<<<8 * gx, 256, 0, stream>>>(X16, Wt, nullptr, h16, 1024, 1024, hstride16, 8,
                                                  As[l], Ad[l], as_buf, ad_buf, N);
        spmm16_kernel<<<dim3(N, 4), 64, 0, stream>>>(
            h16, as_buf, ad_buf, offs, esrc, Bb[l], N, Mp, X16);
    }

    // ---- Layer 3: K=1024 -> h(64), 1 head, fp32 out; alpha fused in GEMM ----
    hipMemsetAsync(Wt, 0, (size_t)128 * 1024 * 2, stream);   // zero cols 64..127 of the padded tile
    transpose_f16<<<dim3(1024 / 32, OUT_DIM / 32), tblk, 0, stream>>>(W[3], Wt, 1024, OUT_DIM);
    hipMemsetAsync(as_buf, 0, abytes, stream);
    hipMemsetAsync(ad_buf, 0, abytes, stream);
    gemm_f16_mfma<<<gx, 256, 0, stream>>>(X16, Wt, bufA, nullptr, OUT_DIM, 1024, 0, 1,
                                          As[3], Ad[3], as_buf, ad_buf, N);
    spmm32_kernel<<<N, 64, 0, stream>>>(
        bufA, as_buf, ad_buf, offs, esrc, Bb[3], N, (float*)d_out);
}